// Round 12
// baseline (101.127 us; speedup 1.0000x reference)
//
#include <hip/hip_runtime.h>

// Patch gather: out[n, r, c] = images[(p0[n] + r) * W + p1[n] + c]
// Fixed geometry: H = W = 4096, width = 128, N = 4096.
//
// R4 base (band-sort + chunked XCD swizzle + dwordx4) with ONE change:
// stores use the SC1 cache-policy bit (device-scope: write-through past the
// per-XCD L2) instead of NT.
// Model from R8-R11: reads are served by per-XCD L2 (band-sort + XCD-chunk
// makes the active read window ~2.6 MB < 4 MB L2). Plain stores allocate in
// L2 and evict that window (plain=90us, hybrid=89.5us). NT stores spare L2
// (reads hit, FETCH 37MB) but also bypass Infinity-Cache write-combining ->
// drain ~4.5 TB/s (66us). SC1-without-NT targets the missing quadrant:
// bypass L2 (reads keep it) while L3 still combines writes (~7 TB/s drain,
// memset-proven).
//
//  1) order_kernel: single-block counting sort by 32-row band (p0>>5).
//  2) patch_gather_kernel: one block per patch in band-sorted order, chunked
//     XCD swizzle, global_store_dwordx4 ... sc1 via inline asm.

#define IMG_W   4096
#define PATCH_W 128
#define F4_PER_PATCH (PATCH_W * PATCH_W / 4)   // 4096
#define BLOCK   256
#define NB      128   // row-band buckets (p0 >> 5, p0 < 4096)

typedef float f32x4 __attribute__((ext_vector_type(4)));

__device__ __forceinline__ void store_sc1(float* p, f32x4 v)
{
    // device-scope store: write-through w.r.t. per-XCD L2, allocates in the
    // memory-side Infinity Cache (no nt bit).
    asm volatile("global_store_dwordx4 %0, %1, off sc1"
                 :: "v"(p), "v"(v) : "memory");
}

__global__ __launch_bounds__(1024) void order_kernel(
    const int* __restrict__ positions, int* __restrict__ order, int N)
{
    __shared__ int hist[NB];
    __shared__ int base[NB];
    const int tid = threadIdx.x;

    for (int b = tid; b < NB; b += blockDim.x) hist[b] = 0;
    __syncthreads();

    for (int i = tid; i < N; i += blockDim.x)
        atomicAdd(&hist[positions[2 * i] >> 5], 1);
    __syncthreads();

    if (tid == 0) {
        int s = 0;
        for (int b = 0; b < NB; ++b) { base[b] = s; s += hist[b]; }
    }
    __syncthreads();

    for (int b = tid; b < NB; b += blockDim.x) hist[b] = base[b];
    __syncthreads();

    for (int i = tid; i < N; i += blockDim.x) {
        const int slot = atomicAdd(&hist[positions[2 * i] >> 5], 1);
        order[slot] = i;
    }
}

__global__ __launch_bounds__(BLOCK) void patch_gather_kernel(
    const float* __restrict__ images,
    const int*   __restrict__ positions,
    const int*   __restrict__ order,     // may be null -> identity order
    float*       __restrict__ out,
    int N)
{
    int slot = blockIdx.x;
    if ((N & 7) == 0) {
        // chunked XCD swizzle: same-(blockIdx&7) blocks share an XCD; give
        // each XCD a contiguous chunk of the band-sorted patch list.
        const int nper = N >> 3;
        slot = (blockIdx.x & 7) * nper + (blockIdx.x >> 3);
    }
    const int n  = order ? order[slot] : slot;
    const int p0 = positions[2 * n];
    const int p1 = positions[2 * n + 1];

    const float* srcp = images + (size_t)p0 * IMG_W + p1;
    float*       dst  = out + (size_t)n * (PATCH_W * PATCH_W);

    #pragma unroll
    for (int it = 0; it < F4_PER_PATCH / BLOCK; ++it) {
        const int i  = it * BLOCK + threadIdx.x;   // float4 index within patch
        const int r  = i >> 5;                     // i / 32 (32 float4 per row)
        const int c  = (i & 31) << 2;              // (i % 32) * 4

        const float* s = srcp + (size_t)r * IMG_W + c;
        f32x4 v;
        v.x = s[0];
        v.y = s[1];
        v.z = s[2];
        v.w = s[3];
        store_sc1(dst + (size_t)r * PATCH_W + c, v);
    }
}

extern "C" void kernel_launch(void* const* d_in, const int* in_sizes, int n_in,
                              void* d_out, int out_size, void* d_ws, size_t ws_size,
                              hipStream_t stream) {
    const float* images    = (const float*)d_in[0];
    const int*   positions = (const int*)d_in[1];
    float* out = (float*)d_out;

    const int N = in_sizes[1] / 2;   // 4096 patches

    int* order = nullptr;
    if (ws_size >= (size_t)N * sizeof(int)) {
        order = (int*)d_ws;
        order_kernel<<<1, 1024, 0, stream>>>(positions, order, N);
    }
    patch_gather_kernel<<<N, BLOCK, 0, stream>>>(images, positions, order, out, N);
}

// Round 13
// 73.662 us; speedup vs baseline: 1.3728x; 1.3728x over previous
//
#include <hip/hip_runtime.h>

// Patch gather, row-major scatter + NT stores.
// out[n, r-p0, c] = images[r, p1+c] for each patch n overlapping image row r.
//
// Fabric model from R8-R12: every schedule saturates ~8.3-9.7 TB/s of
// XCD<->IOD fabric traffic, not HBM. nt+patch-major (65.6us) = 268 wr +
// ~335 cache-served rd = 9.2 TB/s. Plain stores add ~268 MB RFO fills
// (90us). The only way down: software read-dedup (row-scatter: 64 MB
// compulsory reads via block-exclusive LDS staging) + RFO-free writes (nt).
// Fabric ~332 MB -> ~40-50 us. R10 tested this structure with PLAIN stores
// (600 MB fabric incl. RFO -> 89.5us, consistent); nt is the missing bit.
//
//  1) order_kernel (1 block): exact counting sort of patches by p0
//     (4096 bins) -> rec[] {n,p0,p1}, prefix row_start[4097].
//  2) row_scatter_kernel (1024 blocks): block b stages image rows [4b,4b+4)
//     into 64 KB LDS (each image byte read from HBM exactly once), then for
//     each patch with p0 in [4b-127, 4b+3] nt-writes the 1..4 overlapping
//     patch rows; row-PAIRS per dwordx4 instruction = 1 KB contiguous/instr.

#define IMG_W   4096
#define IMG_H   4096
#define PATCH_W 128
#define BLOCK   256
#define ROWS    4
#define NBINS   4096

typedef float f32x4 __attribute__((ext_vector_type(4)));

__global__ __launch_bounds__(1024) void order_kernel(
    const int* __restrict__ positions,
    int4*      __restrict__ rec,
    int*       __restrict__ row_start,   // NBINS+1 ints
    int N)
{
    __shared__ int hist[NBINS];      // 16 KB
    __shared__ int partial[1024];    // 4 KB
    const int tid = threadIdx.x;

    #pragma unroll
    for (int j = 0; j < NBINS / 1024; ++j) hist[tid + j * 1024] = 0;
    __syncthreads();

    for (int i = tid; i < N; i += 1024) {
        const int2 p = ((const int2*)positions)[i];
        atomicAdd(&hist[p.x], 1);
    }
    __syncthreads();

    // two-level exclusive scan: thread t owns bins [4t, 4t+4)
    const int b0 = tid * (NBINS / 1024);
    int s = 0;
    #pragma unroll
    for (int j = 0; j < NBINS / 1024; ++j) s += hist[b0 + j];
    partial[tid] = s;
    __syncthreads();

    for (int off = 1; off < 1024; off <<= 1) {
        const int v   = partial[tid];
        const int add = (tid >= off) ? partial[tid - off] : 0;
        __syncthreads();
        partial[tid] = v + add;
        __syncthreads();
    }

    int running = partial[tid] - s;  // exclusive base of this thread's bins
    #pragma unroll
    for (int j = 0; j < NBINS / 1024; ++j) {
        const int b   = b0 + j;
        const int cnt = hist[b];
        row_start[b] = running;
        hist[b]      = running;      // becomes scatter cursor
        running += cnt;
    }
    if (tid == 1023) row_start[NBINS] = running;   // == N
    __syncthreads();

    for (int i = tid; i < N; i += 1024) {
        const int2 p = ((const int2*)positions)[i];
        const int slot = atomicAdd(&hist[p.x], 1);
        rec[slot] = make_int4(i, p.x, p.y, 0);
    }
}

__global__ __launch_bounds__(BLOCK) void row_scatter_kernel(
    const float* __restrict__ images,
    const int4*  __restrict__ rec,
    const int*   __restrict__ row_start,
    float*       __restrict__ out)
{
    __shared__ float rows[ROWS * IMG_W];   // 64 KB -> 2 blocks/CU
    const int base_r = blockIdx.x * ROWS;

    // stage 4 image rows (block-exclusive: each image byte read once, ever)
    {
        const f32x4* src = (const f32x4*)(images + (size_t)base_r * IMG_W);
        f32x4*       dst = (f32x4*)rows;
        #pragma unroll
        for (int it = 0; it < ROWS * IMG_W / 4 / BLOCK; ++it)   // 16 iters
            dst[it * BLOCK + threadIdx.x] = src[it * BLOCK + threadIdx.x];
    }
    __syncthreads();

    // candidate patches: p0 in [base_r-127, base_r+ROWS-1]
    const int s0 = row_start[max(0, base_r - (PATCH_W - 1))];
    const int s1 = row_start[base_r + ROWS];

    const int wid  = threadIdx.x >> 6;    // wave id 0..3
    const int lane = threadIdx.x & 63;
    const int sub  = lane >> 5;           // row-within-pair: 0/1
    const int c4   = (lane & 31) << 2;    // float col within patch row

    for (int idx = s0 + wid; idx < s1; idx += BLOCK / 64) {
        const int4 rr = rec[idx];         // wave-uniform -> scalar load
        const int n = rr.x, p0 = rr.y, p1 = rr.z;
        const int rlo = max(p0, base_r);
        const int rhi = min(p0 + PATCH_W, base_r + ROWS);
        const int nr  = rhi - rlo;        // 1..4, wave-uniform

        float*       dstp  = out + (size_t)n * (PATCH_W * PATCH_W)
                                 + (size_t)(rlo - p0) * PATCH_W;
        const float* lbase = rows + (rlo - base_r) * IMG_W + p1;

        for (int kk = 0; kk < nr; kk += 2) {
            const int k = kk + sub;       // this half-wave's row
            if (k < nr) {
                const float* l = lbase + k * IMG_W + c4;
                f32x4 v;
                v.x = l[0];
                v.y = l[1];
                v.z = l[2];
                v.w = l[3];
                // paired rows: 64 lanes x 16 B = 1 KB contiguous nt store
                __builtin_nontemporal_store(
                    v, reinterpret_cast<f32x4*>(dstp + (size_t)k * PATCH_W + c4));
            }
        }
    }
}

// Fallback (tiny ws): identity-order nt gather (R3 path, ~89 us, correct).
__global__ __launch_bounds__(BLOCK) void patch_gather_kernel(
    const float* __restrict__ images,
    const int*   __restrict__ positions,
    float*       __restrict__ out)
{
    const int n  = blockIdx.x;
    const int p0 = positions[2 * n];
    const int p1 = positions[2 * n + 1];

    const float* srcp = images + (size_t)p0 * IMG_W + p1;
    float*       dst  = out + (size_t)n * (PATCH_W * PATCH_W);

    #pragma unroll
    for (int it = 0; it < (PATCH_W * PATCH_W / 4) / BLOCK; ++it) {
        const int i = it * BLOCK + threadIdx.x;
        const int r = i >> 5;
        const int c = (i & 31) << 2;
        const float* s = srcp + (size_t)r * IMG_W + c;
        f32x4 v;
        v.x = s[0]; v.y = s[1]; v.z = s[2]; v.w = s[3];
        __builtin_nontemporal_store(
            v, reinterpret_cast<f32x4*>(dst + (size_t)r * PATCH_W + c));
    }
}

extern "C" void kernel_launch(void* const* d_in, const int* in_sizes, int n_in,
                              void* d_out, int out_size, void* d_ws, size_t ws_size,
                              hipStream_t stream) {
    const float* images    = (const float*)d_in[0];
    const int*   positions = (const int*)d_in[1];
    float* out = (float*)d_out;

    const int N = in_sizes[1] / 2;   // 4096 patches

    const size_t rec_off = 32768;    // row_start (16.4 KB) lives at offset 0
    const size_t need    = rec_off + (size_t)N * sizeof(int4);

    if (ws_size >= need) {
        int*  row_start = (int*)d_ws;
        int4* rec       = (int4*)((char*)d_ws + rec_off);
        order_kernel<<<1, 1024, 0, stream>>>(positions, rec, row_start, N);
        row_scatter_kernel<<<IMG_H / ROWS, BLOCK, 0, stream>>>(
            images, rec, row_start, out);
    } else {
        patch_gather_kernel<<<N, BLOCK, 0, stream>>>(images, positions, out);
    }
}